// Round 6
// baseline (715.184 us; speedup 1.0000x reference)
//
#include <hip/hip_runtime.h>

#define N_NODES 100000
#define N_EDGES 3200000
#define F_IN 256
#define CH 16
#define FCN 64

#define NPB 128                          // nodes per bucket
#define NBUCK 782                        // ceil(N_NODES / NPB)
#define NCHUNK 512                       // edge chunks
#define EPB (N_EDGES / NCHUNK)           // 6250 edges per chunk
#define M (NBUCK * NCHUNK)               // 400384 scan elements (div by 1024)
#define NSB (M / 1024)                   // 391 scan blocks

// ---------------- h = x @ w_gcn   [N,256] x [256,16] -> [N,16]
__global__ __launch_bounds__(256) void k_transform(const float* __restrict__ x,
                                                   const float* __restrict__ w,
                                                   float* __restrict__ h) {
    __shared__ float wlds[CH][F_IN + 4];
    int tid = threadIdx.x;
    for (int i = tid; i < F_IN * CH; i += 256) {
        int k = i >> 4, c = i & 15;
        wlds[c][k] = w[i];
    }
    __syncthreads();
    int c = tid & 15;
    int r = tid >> 4;
    int row = blockIdx.x * 16 + r;
    if (row >= N_NODES) return;
    const float4* xr = reinterpret_cast<const float4*>(x + (size_t)row * F_IN);
    const float4* wr = reinterpret_cast<const float4*>(&wlds[c][0]);
    float acc = 0.f;
    #pragma unroll 8
    for (int k4 = 0; k4 < F_IN / 4; ++k4) {
        float4 xv = xr[k4];
        float4 wv = wr[k4];
        acc = fmaf(xv.x, wv.x, acc);
        acc = fmaf(xv.y, wv.y, acc);
        acc = fmaf(xv.z, wv.z, acc);
        acc = fmaf(xv.w, wv.w, acc);
    }
    h[(size_t)row * CH + c] = acc;
}

// ---------------- Phase 1: per-chunk LDS histogram + LDS-atomic rank
__global__ __launch_bounds__(256) void k_hist_rank(const int* __restrict__ ei,
                                                   unsigned short* __restrict__ rank16,
                                                   int* __restrict__ histM) {   // [NBUCK][NCHUNK]
    __shared__ int hist[NBUCK];
    int t = threadIdx.x, k = blockIdx.x;
    for (int i = t; i < NBUCK; i += 256) hist[i] = 0;
    __syncthreads();
    int base = k * EPB;
    for (int i = t; i < EPB; i += 256) {
        int e = base + i;
        int dst = ei[N_EDGES + e];
        int r = atomicAdd(&hist[dst >> 7], 1);       // LDS returning atomic
        rank16[e] = (unsigned short)r;
    }
    __syncthreads();
    for (int i = t; i < NBUCK; i += 256) histM[(size_t)i * NCHUNK + k] = hist[i];
}

// ---------------- Scan pass 1: 1024-elem chunk sums -> partials[NSB]
__global__ __launch_bounds__(256) void k_scanP1(const int* __restrict__ histM,
                                                int* __restrict__ partials) {
    __shared__ int wsum[4];
    int t = threadIdx.x;
    int4 v = reinterpret_cast<const int4*>(histM)[blockIdx.x * 256 + t];
    int s = v.x + v.y + v.z + v.w;
    #pragma unroll
    for (int off = 32; off > 0; off >>= 1) s += __shfl_xor(s, off, 64);
    if ((t & 63) == 0) wsum[t >> 6] = s;
    __syncthreads();
    if (t == 0) partials[blockIdx.x] = wsum[0] + wsum[1] + wsum[2] + wsum[3];
}

// ---------------- Scan pass 2: exclusive scan of NSB partials -> bases[NSB+1]
__global__ __launch_bounds__(512) void k_scanP2(const int* __restrict__ partials,
                                                int* __restrict__ bases) {
    __shared__ int wsum[8];
    int t = threadIdx.x;
    int v = (t < NSB) ? partials[t] : 0;
    int lane = t & 63, w = t >> 6;
    int incl = v;
    #pragma unroll
    for (int off = 1; off < 64; off <<= 1) {
        int u = __shfl_up(incl, off, 64);
        if (lane >= off) incl += u;
    }
    if (lane == 63) wsum[w] = incl;
    __syncthreads();
    if (t == 0) {
        int s = 0;
        #pragma unroll
        for (int i = 0; i < 8; ++i) { int u = wsum[i]; wsum[i] = s; s += u; }
    }
    __syncthreads();
    int excl = incl - v + wsum[w];
    if (t < NSB) {
        bases[t] = excl;
        if (t == NSB - 1) bases[NSB] = excl + v;
    }
}

// ---------------- Scan pass 3: local re-scan + base -> offs2d[M+1] (exclusive)
__global__ __launch_bounds__(256) void k_scanP3(const int* __restrict__ histM,
                                                const int* __restrict__ bases,
                                                int* __restrict__ offs2d) {
    __shared__ int wsum[4];
    int t = threadIdx.x;
    int gi = blockIdx.x * 256 + t;
    int4 v = reinterpret_cast<const int4*>(histM)[gi];
    int s = v.x + v.y + v.z + v.w;
    int lane = t & 63, w = t >> 6;
    int incl = s;
    #pragma unroll
    for (int off = 1; off < 64; off <<= 1) {
        int u = __shfl_up(incl, off, 64);
        if (lane >= off) incl += u;
    }
    if (lane == 63) wsum[w] = incl;
    __syncthreads();
    if (t == 0) {
        int a = wsum[0], b = wsum[1], c = wsum[2];
        wsum[0] = 0; wsum[1] = a; wsum[2] = a + b; wsum[3] = a + b + c;
    }
    __syncthreads();
    int excl = incl - s + wsum[w] + bases[blockIdx.x];
    int4 o;
    o.x = excl;
    o.y = excl + v.x;
    o.z = o.y + v.y;
    o.w = o.z + v.z;
    reinterpret_cast<int4*>(offs2d)[gi] = o;
    if (blockIdx.x == 0 && t == 0) offs2d[M] = bases[NSB];
}

// ---------------- Phase 2: deterministic record scatter — zero atomics
__global__ __launch_bounds__(256) void k_scatter2(const int* __restrict__ ei,
                                                  const float* __restrict__ ew,
                                                  const unsigned short* __restrict__ rank16,
                                                  const int* __restrict__ offs2d,
                                                  int2* __restrict__ recs) {
    int t = threadIdx.x, k = blockIdx.x;
    int base = k * EPB;
    for (int i = t; i < EPB; i += 256) {
        int e = base + i;
        int src = ei[e];
        int dst = ei[N_EDGES + e];
        int b = dst >> 7;
        int local = dst & (NPB - 1);
        int pos = offs2d[(size_t)b * NCHUNK + k] + (int)rank16[e];
        int2 r;
        r.x = src | (local << 17);                 // src < 2^17, local < 2^7
        r.y = __float_as_int(ew[e]);
        recs[pos] = r;
    }
}

// ---------------- Phase 3: bucket aggregation in LDS + fused FCN head
__global__ __launch_bounds__(256) void k_agg_head(const int2* __restrict__ recs,
                                                  const int* __restrict__ offs2d,
                                                  const float* __restrict__ h,
                                                  const float* __restrict__ w0,  // [16][64]
                                                  const float* __restrict__ b0,  // [64]
                                                  const float* __restrict__ w1,  // [64]
                                                  const float* __restrict__ b1,  // [1]
                                                  float* __restrict__ out) {     // [N]
    __shared__ float acc[NPB * CH];      // 8 KB
    __shared__ float w0s[CH * FCN];      // 4 KB
    __shared__ float w1s[FCN];
    int t = threadIdx.x;
    int b = blockIdx.x;
    for (int i = t; i < NPB * CH; i += 256) acc[i] = 0.f;
    for (int i = t; i < CH * FCN; i += 256) w0s[i] = w0[i];
    if (t < FCN) w1s[t] = w1[t];
    __syncthreads();
    int start = offs2d[(size_t)b * NCHUNK];
    int end   = offs2d[(size_t)(b + 1) * NCHUNK];      // b=NBUCK-1 hits offs2d[M]=total
    int c = t & 15, g = t >> 4;                        // 16 records in flight per block-iter
    for (int j = start + g; j < end; j += 16) {
        int2 r = recs[j];                              // broadcast over 16 lanes
        int src   = r.x & 0x1FFFF;
        int local = r.x >> 17;
        float wv  = __int_as_float(r.y);
        float hv  = h[(size_t)src * CH + c];           // 16 lanes = one full 64B row
        atomicAdd(&acc[local * CH + c], hv * wv);      // ds_add_f32, non-returning
    }
    __syncthreads();
    // head: 4 waves x 32 nodes
    int lane = t & 63, wv4 = t >> 6;
    for (int nl = wv4 * 32; nl < wv4 * 32 + 32; ++nl) {
        int node = b * NPB + nl;
        if (node >= N_NODES) break;
        float o1 = b0[lane];
        #pragma unroll
        for (int kk = 0; kk < CH; ++kk) {
            float a = fmaxf(acc[nl * CH + kk], 0.f);   // LDS broadcast
            o1 = fmaf(a, w0s[kk * FCN + lane], o1);
        }
        o1 = fmaxf(o1, 0.f);
        float y = o1 * w1s[lane];
        #pragma unroll
        for (int off = 32; off > 0; off >>= 1) y += __shfl_xor(y, off, 64);
        if (lane == 0) out[node] = y + b1[0];
    }
}

// ---------------- Fallback path (ws too small): device atomics
__global__ __launch_bounds__(256) void k_scatter_fb(const int* __restrict__ ei,
                                                    const float* __restrict__ ew,
                                                    const float* __restrict__ h,
                                                    float* __restrict__ agg) {
    long long t = (long long)blockIdx.x * 256 + threadIdx.x;
    int e = (int)(t >> 2);
    int g = (int)(t & 3);
    if (e >= N_EDGES) return;
    int src = ei[e];
    int dst = ei[N_EDGES + e];
    float w = ew[e];
    float4 hv = reinterpret_cast<const float4*>(h)[src * 4 + g];
    float* ap = agg + (size_t)dst * CH + g * 4;
    atomicAdd(ap + 0, hv.x * w);
    atomicAdd(ap + 1, hv.y * w);
    atomicAdd(ap + 2, hv.z * w);
    atomicAdd(ap + 3, hv.w * w);
}

__global__ __launch_bounds__(256) void k_head_fb(const float* __restrict__ agg,
                                                 const float* __restrict__ w0,
                                                 const float* __restrict__ b0,
                                                 const float* __restrict__ w1,
                                                 const float* __restrict__ b1,
                                                 float* __restrict__ out) {
    __shared__ float w0s[CH * FCN];
    __shared__ float w1s[FCN];
    int tid = threadIdx.x;
    for (int i = tid; i < CH * FCN; i += 256) w0s[i] = w0[i];
    if (tid < FCN) w1s[tid] = w1[tid];
    __syncthreads();
    int lane = tid & 63;
    int wv = tid >> 6;
    int node = blockIdx.x * 4 + wv;
    if (node >= N_NODES) return;
    const float* an = agg + (size_t)node * CH;
    float o1 = b0[lane];
    #pragma unroll
    for (int k = 0; k < CH; ++k) {
        float a = fmaxf(an[k], 0.f);
        o1 = fmaf(a, w0s[k * FCN + lane], o1);
    }
    o1 = fmaxf(o1, 0.f);
    float y = o1 * w1s[lane];
    #pragma unroll
    for (int off = 32; off > 0; off >>= 1) y += __shfl_xor(y, off, 64);
    if (lane == 0) out[node] = y + b1[0];
}

extern "C" void kernel_launch(void* const* d_in, const int* in_sizes, int n_in,
                              void* d_out, int out_size, void* d_ws, size_t ws_size,
                              hipStream_t stream) {
    const float* x  = (const float*)d_in[0];
    const int*   ei = (const int*)  d_in[1];
    const float* ew = (const float*)d_in[2];
    const float* wg = (const float*)d_in[3];
    const float* w0 = (const float*)d_in[4];
    const float* b0 = (const float*)d_in[5];
    const float* w1 = (const float*)d_in[6];
    const float* b1 = (const float*)d_in[7];
    float* out = (float*)d_out;

    // ---- workspace layout (256B-aligned segments) ----
    char* p = (char*)d_ws;
    float* h = (float*)p;                        p += (size_t)N_NODES * CH * 4;     // 6.4 MB
    unsigned short* rank16 = (unsigned short*)p; p += (size_t)N_EDGES * 2;          // 6.4 MB
    int* histM = (int*)p;                        p += (size_t)M * 4;                // 1.6 MB (16B-aligned)
    int* offs2d = (int*)p;                       p += 1601792;                      // (M+1)*4 padded
    int* partials = (int*)p;                     p += 2048;                         // NSB ints padded
    int* bases = (int*)p;                        p += 2048;                         // NSB+1 ints padded
    int2* recs = (int2*)p;                       p += (size_t)N_EDGES * 8;          // 25.6 MB
    const size_t need = (size_t)(p - (char*)d_ws);

    if (ws_size >= need) {
        k_transform<<<(N_NODES + 15) / 16, 256, 0, stream>>>(x, wg, h);
        k_hist_rank<<<NCHUNK, 256, 0, stream>>>(ei, rank16, histM);
        k_scanP1<<<NSB, 256, 0, stream>>>(histM, partials);
        k_scanP2<<<1, 512, 0, stream>>>(partials, bases);
        k_scanP3<<<NSB, 256, 0, stream>>>(histM, bases, offs2d);
        k_scatter2<<<NCHUNK, 256, 0, stream>>>(ei, ew, rank16, offs2d, recs);
        k_agg_head<<<NBUCK, 256, 0, stream>>>(recs, offs2d, h, w0, b0, w1, b1, out);
    } else {
        float* agg = (float*)((char*)d_ws + (size_t)N_NODES * CH * 4);
        hipMemsetAsync(agg, 0, (size_t)N_NODES * CH * 4, stream);
        k_transform<<<(N_NODES + 15) / 16, 256, 0, stream>>>(x, wg, h);
        long long sc_threads = (long long)N_EDGES * 4;
        k_scatter_fb<<<(int)((sc_threads + 255) / 256), 256, 0, stream>>>(ei, ew, h, agg);
        k_head_fb<<<(N_NODES + 3) / 4, 256, 0, stream>>>(agg, w0, b0, w1, b1, out);
    }
}

// Round 7
// 663.193 us; speedup vs baseline: 1.0784x; 1.0784x over previous
//
#include <hip/hip_runtime.h>

#define N_NODES 100000
#define N_EDGES 3200000
#define F_IN 256
#define CH 16
#define FCN 64

#define NPB 64                           // nodes per bucket
#define NBUCK 1563                       // ceil(N_NODES / NPB)
#define NCHUNK 1024                      // edge chunks
#define EPB (N_EDGES / NCHUNK)           // 3125 edges per chunk
#define M (NBUCK * NCHUNK)               // 1600512 scan cells (div by 1024)
#define NSB (M / 1024)                   // 1563 scan blocks
#define ACCP 17                          // padded acc stride (bank spread)

// ---------------- h = x @ w_gcn   [N,256] x [256,16] -> [N,16]
__global__ __launch_bounds__(256) void k_transform(const float* __restrict__ x,
                                                   const float* __restrict__ w,
                                                   float* __restrict__ h) {
    __shared__ float wlds[CH][F_IN + 4];
    int tid = threadIdx.x;
    for (int i = tid; i < F_IN * CH; i += 256) {
        int k = i >> 4, c = i & 15;
        wlds[c][k] = w[i];
    }
    __syncthreads();
    int c = tid & 15;
    int r = tid >> 4;
    int row = blockIdx.x * 16 + r;
    if (row >= N_NODES) return;
    const float4* xr = reinterpret_cast<const float4*>(x + (size_t)row * F_IN);
    const float4* wr = reinterpret_cast<const float4*>(&wlds[c][0]);
    float acc = 0.f;
    #pragma unroll 8
    for (int k4 = 0; k4 < F_IN / 4; ++k4) {
        float4 xv = xr[k4];
        float4 wv = wr[k4];
        acc = fmaf(xv.x, wv.x, acc);
        acc = fmaf(xv.y, wv.y, acc);
        acc = fmaf(xv.z, wv.z, acc);
        acc = fmaf(xv.w, wv.w, acc);
    }
    h[(size_t)row * CH + c] = acc;
}

// ---------------- Phase 1: per-chunk LDS histogram + LDS-atomic rank (1024 blocks)
__global__ __launch_bounds__(256) void k_hist_rank(const int* __restrict__ ei,
                                                   unsigned short* __restrict__ rank16,
                                                   int* __restrict__ histM) {   // [NBUCK][NCHUNK]
    __shared__ int hist[NBUCK];
    int t = threadIdx.x, k = blockIdx.x;
    for (int i = t; i < NBUCK; i += 256) hist[i] = 0;
    __syncthreads();
    int base = k * EPB;
    for (int i = t; i < EPB; i += 256) {
        int e = base + i;
        int dst = ei[N_EDGES + e];
        int r = atomicAdd(&hist[dst >> 6], 1);       // LDS returning atomic
        rank16[e] = (unsigned short)r;
    }
    __syncthreads();
    for (int i = t; i < NBUCK; i += 256) histM[(size_t)i * NCHUNK + k] = hist[i];
}

// ---------------- Scan pass 1: 1024-cell block sums -> partials[NSB]
__global__ __launch_bounds__(256) void k_scanP1(const int* __restrict__ histM,
                                                int* __restrict__ partials) {
    __shared__ int wsum[4];
    int t = threadIdx.x;
    int4 v = reinterpret_cast<const int4*>(histM)[blockIdx.x * 256 + t];
    int s = v.x + v.y + v.z + v.w;
    #pragma unroll
    for (int off = 32; off > 0; off >>= 1) s += __shfl_xor(s, off, 64);
    if ((t & 63) == 0) wsum[t >> 6] = s;
    __syncthreads();
    if (t == 0) partials[blockIdx.x] = wsum[0] + wsum[1] + wsum[2] + wsum[3];
}

// ---------------- Scan pass 2: exclusive scan of NSB=1563 partials (1 block, 2/thread)
__global__ __launch_bounds__(1024) void k_scanP2(const int* __restrict__ partials,
                                                 int* __restrict__ bases) {
    __shared__ int wsum[16];
    int t = threadIdx.x;
    int i0 = 2 * t, i1 = 2 * t + 1;
    int a = (i0 < NSB) ? partials[i0] : 0;
    int b = (i1 < NSB) ? partials[i1] : 0;
    int s = a + b;
    int lane = t & 63, w = t >> 6;
    int incl = s;
    #pragma unroll
    for (int off = 1; off < 64; off <<= 1) {
        int u = __shfl_up(incl, off, 64);
        if (lane >= off) incl += u;
    }
    if (lane == 63) wsum[w] = incl;
    __syncthreads();
    if (t == 0) {
        int run = 0;
        #pragma unroll
        for (int i = 0; i < 16; ++i) { int u = wsum[i]; wsum[i] = run; run += u; }
    }
    __syncthreads();
    int excl = incl - s + wsum[w];
    if (i0 <= NSB) bases[i0] = excl;
    if (i1 <= NSB) bases[i1] = excl + a;
}

// ---------------- Scan pass 3: local re-scan + base -> offs2d[M+1] (exclusive)
__global__ __launch_bounds__(256) void k_scanP3(const int* __restrict__ histM,
                                                const int* __restrict__ bases,
                                                int* __restrict__ offs2d) {
    __shared__ int wsum[4];
    int t = threadIdx.x;
    int gi = blockIdx.x * 256 + t;
    int4 v = reinterpret_cast<const int4*>(histM)[gi];
    int s = v.x + v.y + v.z + v.w;
    int lane = t & 63, w = t >> 6;
    int incl = s;
    #pragma unroll
    for (int off = 1; off < 64; off <<= 1) {
        int u = __shfl_up(incl, off, 64);
        if (lane >= off) incl += u;
    }
    if (lane == 63) wsum[w] = incl;
    __syncthreads();
    if (t == 0) {
        int a = wsum[0], b = wsum[1], c = wsum[2];
        wsum[0] = 0; wsum[1] = a; wsum[2] = a + b; wsum[3] = a + b + c;
    }
    __syncthreads();
    int excl = incl - s + wsum[w] + bases[blockIdx.x];
    int4 o;
    o.x = excl;
    o.y = excl + v.x;
    o.z = o.y + v.y;
    o.w = o.z + v.z;
    reinterpret_cast<int4*>(offs2d)[gi] = o;
    if (blockIdx.x == 0 && t == 0) offs2d[M] = bases[NSB];
}

// ---------------- Phase 2: deterministic record scatter — zero atomics (1024 blocks)
__global__ __launch_bounds__(256) void k_scatter2(const int* __restrict__ ei,
                                                  const float* __restrict__ ew,
                                                  const unsigned short* __restrict__ rank16,
                                                  const int* __restrict__ offs2d,
                                                  int2* __restrict__ recs) {
    __shared__ int coffs[NBUCK];
    int t = threadIdx.x, k = blockIdx.x;
    for (int i = t; i < NBUCK; i += 256) coffs[i] = offs2d[(size_t)i * NCHUNK + k];
    __syncthreads();
    int base = k * EPB;
    for (int i = t; i < EPB; i += 256) {
        int e = base + i;
        int src = ei[e];
        int dst = ei[N_EDGES + e];
        int b = dst >> 6;
        int local = dst & (NPB - 1);
        int pos = coffs[b] + (int)rank16[e];
        int2 r;
        r.x = src | (local << 17);                 // src < 2^17, local < 2^6
        r.y = __float_as_int(ew[e]);
        recs[pos] = r;
    }
}

// ---------------- Phase 3: bucket aggregation (4 lanes/record) + fused FCN head
__global__ __launch_bounds__(256) void k_agg_head(const int2* __restrict__ recs,
                                                  const int* __restrict__ offs2d,
                                                  const float* __restrict__ h,
                                                  const float* __restrict__ w0,  // [16][64]
                                                  const float* __restrict__ b0,  // [64]
                                                  const float* __restrict__ w1,  // [64]
                                                  const float* __restrict__ b1,  // [1]
                                                  float* __restrict__ out) {     // [N]
    __shared__ float acc[NPB * ACCP];    // 4.25 KB, padded stride
    __shared__ float w0s[CH * FCN];      // 4 KB
    __shared__ float w1s[FCN];
    int t = threadIdx.x;
    int b = blockIdx.x;
    for (int i = t; i < NPB * ACCP; i += 256) acc[i] = 0.f;
    for (int i = t; i < CH * FCN; i += 256) w0s[i] = w0[i];
    if (t < FCN) w1s[t] = w1[t];
    __syncthreads();
    int start = offs2d[(size_t)b * NCHUNK];
    int end   = offs2d[(size_t)(b + 1) * NCHUNK];
    int q = t & 3, rs = t >> 2;                    // 64 records in flight per block-iter
    for (int j = start + rs; j < end; j += 64) {
        int2 r = recs[j];                          // 4 lanes broadcast one 8B record
        int src   = r.x & 0x1FFFF;
        int local = r.x >> 17;
        float wv  = __int_as_float(r.y);
        float4 hv = reinterpret_cast<const float4*>(h)[src * 4 + q];  // 16 lines/wave in flight
        float* a = &acc[local * ACCP + q * 4];
        atomicAdd(a + 0, hv.x * wv);               // ds_add_f32, non-returning
        atomicAdd(a + 1, hv.y * wv);
        atomicAdd(a + 2, hv.z * wv);
        atomicAdd(a + 3, hv.w * wv);
    }
    __syncthreads();
    // head: 4 waves x 16 nodes
    int lane = t & 63, wv4 = t >> 6;
    float bb = b0[lane];
    float w1l = w1s[lane];
    float bias1 = b1[0];
    for (int nl = wv4 * 16; nl < wv4 * 16 + 16; ++nl) {
        int node = b * NPB + nl;
        if (node >= N_NODES) break;
        float o1 = bb;
        #pragma unroll
        for (int kk = 0; kk < CH; ++kk) {
            float a = fmaxf(acc[nl * ACCP + kk], 0.f);   // LDS broadcast
            o1 = fmaf(a, w0s[kk * FCN + lane], o1);
        }
        o1 = fmaxf(o1, 0.f);
        float y = o1 * w1l;
        #pragma unroll
        for (int off = 32; off > 0; off >>= 1) y += __shfl_xor(y, off, 64);
        if (lane == 0) out[node] = y + bias1;
    }
}

// ---------------- Fallback path (ws too small): device atomics
__global__ __launch_bounds__(256) void k_scatter_fb(const int* __restrict__ ei,
                                                    const float* __restrict__ ew,
                                                    const float* __restrict__ h,
                                                    float* __restrict__ agg) {
    long long t = (long long)blockIdx.x * 256 + threadIdx.x;
    int e = (int)(t >> 2);
    int g = (int)(t & 3);
    if (e >= N_EDGES) return;
    int src = ei[e];
    int dst = ei[N_EDGES + e];
    float w = ew[e];
    float4 hv = reinterpret_cast<const float4*>(h)[src * 4 + g];
    float* ap = agg + (size_t)dst * CH + g * 4;
    atomicAdd(ap + 0, hv.x * w);
    atomicAdd(ap + 1, hv.y * w);
    atomicAdd(ap + 2, hv.z * w);
    atomicAdd(ap + 3, hv.w * w);
}

__global__ __launch_bounds__(256) void k_head_fb(const float* __restrict__ agg,
                                                 const float* __restrict__ w0,
                                                 const float* __restrict__ b0,
                                                 const float* __restrict__ w1,
                                                 const float* __restrict__ b1,
                                                 float* __restrict__ out) {
    __shared__ float w0s[CH * FCN];
    __shared__ float w1s[FCN];
    int tid = threadIdx.x;
    for (int i = tid; i < CH * FCN; i += 256) w0s[i] = w0[i];
    if (tid < FCN) w1s[tid] = w1[tid];
    __syncthreads();
    int lane = tid & 63;
    int wv = tid >> 6;
    int node = blockIdx.x * 4 + wv;
    if (node >= N_NODES) return;
    const float* an = agg + (size_t)node * CH;
    float o1 = b0[lane];
    #pragma unroll
    for (int k = 0; k < CH; ++k) {
        float a = fmaxf(an[k], 0.f);
        o1 = fmaf(a, w0s[k * FCN + lane], o1);
    }
    o1 = fmaxf(o1, 0.f);
    float y = o1 * w1s[lane];
    #pragma unroll
    for (int off = 32; off > 0; off >>= 1) y += __shfl_xor(y, off, 64);
    if (lane == 0) out[node] = y + b1[0];
}

extern "C" void kernel_launch(void* const* d_in, const int* in_sizes, int n_in,
                              void* d_out, int out_size, void* d_ws, size_t ws_size,
                              hipStream_t stream) {
    const float* x  = (const float*)d_in[0];
    const int*   ei = (const int*)  d_in[1];
    const float* ew = (const float*)d_in[2];
    const float* wg = (const float*)d_in[3];
    const float* w0 = (const float*)d_in[4];
    const float* b0 = (const float*)d_in[5];
    const float* w1 = (const float*)d_in[6];
    const float* b1 = (const float*)d_in[7];
    float* out = (float*)d_out;

    // ---- workspace layout (256B-aligned segments) ----
    char* p = (char*)d_ws;
    float* h = (float*)p;                        p += 6400000;                 // [N][16]
    unsigned short* rank16 = (unsigned short*)p; p += 6400000;                 // [E] u16
    int* histM = (int*)p;                        p += (size_t)M * 4;           // 6.4 MB (256-mult)
    int* offs2d = (int*)p;                       p += 6402304;                 // (M+1)*4 padded
    int* partials = (int*)p;                     p += 6400;                    // NSB ints padded
    int* bases = (int*)p;                        p += 6400;                    // NSB+1 ints padded
    int2* recs = (int2*)p;                       p += (size_t)N_EDGES * 8;     // 25.6 MB
    const size_t need = (size_t)(p - (char*)d_ws);

    if (ws_size >= need) {
        k_transform<<<(N_NODES + 15) / 16, 256, 0, stream>>>(x, wg, h);
        k_hist_rank<<<NCHUNK, 256, 0, stream>>>(ei, rank16, histM);
        k_scanP1<<<NSB, 256, 0, stream>>>(histM, partials);
        k_scanP2<<<1, 1024, 0, stream>>>(partials, bases);
        k_scanP3<<<NSB, 256, 0, stream>>>(histM, bases, offs2d);
        k_scatter2<<<NCHUNK, 256, 0, stream>>>(ei, ew, rank16, offs2d, recs);
        k_agg_head<<<NBUCK, 256, 0, stream>>>(recs, offs2d, h, w0, b0, w1, b1, out);
    } else {
        float* agg = (float*)((char*)d_ws + 6400000);
        hipMemsetAsync(agg, 0, (size_t)N_NODES * CH * 4, stream);
        k_transform<<<(N_NODES + 15) / 16, 256, 0, stream>>>(x, wg, h);
        long long sc_threads = (long long)N_EDGES * 4;
        k_scatter_fb<<<(int)((sc_threads + 255) / 256), 256, 0, stream>>>(ei, ew, h, agg);
        k_head_fb<<<(N_NODES + 3) / 4, 256, 0, stream>>>(agg, w0, b0, w1, b1, out);
    }
}